// Round 12
// baseline (302.378 us; speedup 1.0000x reference)
//
#include <hip/hip_runtime.h>

// ---------------------------------------------------------------------------
// MultiHeadsLinearAttention  (B=8, C=512, HEADS=8, CH=64, H=W=64 -> N=4096)
// Inputs fp32, output fp32. Compute: bf16 MFMA, fp32 accumulation.
//
// Dataflow (outgemm eliminated by associativity, R8):
//   y = Wf @ (qsm @ attnF)  ==  (Wf_h @ attnF_h per head) @ qsm = Wff_b @ qsm
// Stages (full-ws mode):
//  T : norm+transpose (+fused weight convert); xnT[p][c] bf16
//  C : QKV GEMM (128x128, BK=64, gload_lds + R7 source-permutation swizzle);
//      Q path fuses q-softmax on fp32 acc (R11: register-resident softmax,
//      1 LDS read pass instead of 3), stores qsm [p][c]; K,V -> d_out
//  D : k-softmax stats (kmax,kinv)
//  E : attnP partials. R11: ks split 8->16 slices (grid 1024 = 4 blocks/CU;
//      was 2/CU -> latency-bound, G1). Wave-specialized, zero atomics.
//  M : wmix self-sums 16 attnP partials (L2-hot), folds kinv, computes
//      Wff[b][o][h*64+c] -> d_out base (K/V dead)
//  G : FFN GEMM y = ffn_b + Wff_b @ qsm -> bf16 y into dead xnT region;
//      ysq from bf16-rounded y (R7-consistent numerics)
//  H : final: out = y*inv(||col||)*g2*sqrtC + x -> d_out (write-only)
// Chunk-ws fallback keeps the R9 pipeline (flagged paths, 16-slice attnsum).
//
// R7: swizzle pairing verified on HW (bank conflicts 19.3M -> 393K).
// R9 lesson: fp32-y was a hidden regression. R10: hit predicted 294.
// m99-m141: 128^2 2-barrier GEMM at structural ceiling (~630 TF @ K=512).
// NOTE: identical source hit "container failed twice" last round — third
// acquisition-layer flake (R2/R8 precedent: passed on resubmission). Full
// re-audit of the R11 diff (bounds, guards, aliasing) found no defect ->
// resubmitted unchanged.
// ---------------------------------------------------------------------------

typedef __bf16 bf16_t;
typedef __bf16 bf8 __attribute__((ext_vector_type(8)));
typedef float f32x4 __attribute__((ext_vector_type(4)));

#define NC 512
#define NP 4096
#define SQRTC 22.62741699796952f
#define QSCALE 0.125f
#define QSTRIDE  ((size_t)NC * NP)      // 2097152  per-batch 512-row elems
#define KVSTRIDE ((size_t)1024 * NP)    // 4194304  per-batch kv elems (d_out)
#define LDC 136                          // epilogue C-tile stride (bank-spread)
#define NKS 16                           // attn p-slices (R11: was 8)

__device__ inline unsigned short bfbits(__bf16 h) {
    return __builtin_bit_cast(unsigned short, h);
}

// async global->LDS, 16B per lane. LDS dest wave-uniform base + lane*16.
__device__ __forceinline__ void gload_lds16(const bf16_t* g, __bf16* l) {
    __builtin_amdgcn_global_load_lds(
        (const __attribute__((address_space(1))) void*)g,
        (__attribute__((address_space(3))) void*)l, 16, 0, 0);
}

// ---------------------------------------------------------------------------
// W (chunk fallback only): both weight converts.
// ---------------------------------------------------------------------------
__global__ __launch_bounds__(256) void
wconv_kernel(const float* __restrict__ qkv_w, const float* __restrict__ g,
             const float* __restrict__ ffn_w, bf16_t* __restrict__ Wg,
             bf16_t* __restrict__ Wf) {
    const int bx = blockIdx.x;
    if (bx < 768) {
        int i0 = (bx * 256 + threadIdx.x) * 4;
        float4 wv = *(const float4*)&qkv_w[i0];
        const float4 gv = *(const float4*)&g[i0 & 511];
        ushort4 o;
        o.x = bfbits((__bf16)(wv.x * gv.x));
        o.y = bfbits((__bf16)(wv.y * gv.y));
        o.z = bfbits((__bf16)(wv.z * gv.z));
        o.w = bfbits((__bf16)(wv.w * gv.w));
        *(ushort4*)&Wg[i0] = o;
    } else {
        int i0 = ((bx - 768) * 256 + threadIdx.x) * 4;
        float4 wv = *(const float4*)&ffn_w[i0];
        ushort4 o;
        o.x = bfbits((__bf16)wv.x);
        o.y = bfbits((__bf16)wv.y);
        o.z = bfbits((__bf16)wv.z);
        o.w = bfbits((__bf16)wv.w);
        *(ushort4*)&Wf[i0] = o;
    }
}

// ---------------------------------------------------------------------------
// T: norm + transpose (+ optional fused weight convert in blocks bid<512).
// grid(128, nb) block 512. xnT[p][c] = x[c][p] * sqrtC/max(||x[:,p]||,eps)
// ---------------------------------------------------------------------------
__global__ __launch_bounds__(512) void
norm_transpose_kernel(const float* __restrict__ x, bf16_t* __restrict__ xnT,
                      const float* __restrict__ qkv_w, const float* __restrict__ g,
                      const float* __restrict__ ffn_w, bf16_t* __restrict__ Wg,
                      bf16_t* __restrict__ Wf, int doW) {
    const int bl = blockIdx.y;
    const int p0 = blockIdx.x * 32;
    const int t = threadIdx.x;

    if (doW) {                            // fused weight convert (full mode)
        const int bid = blockIdx.y * 128 + blockIdx.x;
        if (bid < 512) {
            int i0 = bid * 2048 + t * 4;  // blocks 0..383 qkv, 384..511 ffn
            if (i0 < 786432) {
                float4 wv = *(const float4*)&qkv_w[i0];
                const float4 gv = *(const float4*)&g[i0 & 511];
                ushort4 o;
                o.x = bfbits((__bf16)(wv.x * gv.x));
                o.y = bfbits((__bf16)(wv.y * gv.y));
                o.z = bfbits((__bf16)(wv.z * gv.z));
                o.w = bfbits((__bf16)(wv.w * gv.w));
                *(ushort4*)&Wg[i0] = o;
            } else {
                int j0 = i0 - 786432;
                float4 wv = *(const float4*)&ffn_w[j0];
                ushort4 o;
                o.x = bfbits((__bf16)wv.x);
                o.y = bfbits((__bf16)wv.y);
                o.z = bfbits((__bf16)wv.z);
                o.w = bfbits((__bf16)wv.w);
                *(ushort4*)&Wf[j0] = o;
            }
        }
    }

    const float* xb = x + (size_t)bl * QSTRIDE;
    bf16_t* ob = xnT + (size_t)bl * QSTRIDE;

    // pass 1: sumsq, float4 coalesced + shfl_xor tree
    const int cg = t & 7, r0 = t >> 3;
    f32x4 ss = {0.f, 0.f, 0.f, 0.f};
    #pragma unroll
    for (int k = 0; k < 8; ++k) {
        const int c = r0 + k * 64;
        float4 v = *(const float4*)&xb[(size_t)c * NP + p0 + cg * 4];
        ss.x += v.x * v.x; ss.y += v.y * v.y;
        ss.z += v.z * v.z; ss.w += v.w * v.w;
    }
    #pragma unroll
    for (int m = 8; m <= 32; m <<= 1) {
        ss.x += __shfl_xor(ss.x, m); ss.y += __shfl_xor(ss.y, m);
        ss.z += __shfl_xor(ss.z, m); ss.w += __shfl_xor(ss.w, m);
    }
    __shared__ float sP[8][34];
    __shared__ float sInv[32];
    const int w = t >> 6;
    if ((t & 63) < 8) {
        const int p = (t & 7) * 4;
        sP[w][p] = ss.x; sP[w][p + 1] = ss.y;
        sP[w][p + 2] = ss.z; sP[w][p + 3] = ss.w;
    }
    __syncthreads();
    if (t < 32) {
        float tot = 0.f;
        #pragma unroll
        for (int j = 0; j < 8; ++j) tot += sP[j][t];
        sInv[t] = SQRTC / fmaxf(sqrtf(tot), 1e-12f);
    }
    __syncthreads();

    // pass 2: 128-c x 32-p chunks through LDS transpose, float4 loads
    __shared__ __bf16 sT[128][41];
    for (int cc = 0; cc < 512; cc += 128) {
        #pragma unroll
        for (int j = 0; j < 2; ++j) {
            int idx = t + j * 512;               // [0,1024): 128 cr x 8 pg
            int cr = idx >> 3, pg = idx & 7;
            float4 v = *(const float4*)&xb[(size_t)(cc + cr) * NP + p0 + pg * 4];
            sT[cr][pg * 4 + 0] = (__bf16)(v.x * sInv[pg * 4 + 0]);
            sT[cr][pg * 4 + 1] = (__bf16)(v.y * sInv[pg * 4 + 1]);
            sT[cr][pg * 4 + 2] = (__bf16)(v.z * sInv[pg * 4 + 2]);
            sT[cr][pg * 4 + 3] = (__bf16)(v.w * sInv[pg * 4 + 3]);
        }
        __syncthreads();
        {
            int p = t >> 4, c8 = (t & 15) * 8;
            bf8 v;
            #pragma unroll
            for (int q = 0; q < 8; ++q) v[q] = sT[c8 + q][p];
            *(bf8*)&ob[(size_t)(p0 + p) * NC + cc + c8] = v;
        }
        __syncthreads();
    }
}

// ---------------------------------------------------------------------------
// C: QKV GEMM. grid(32, 12, nb) block 256.
// bm<4: Q path — register-resident softmax epilogue, store qsm [p][c].
// bm>=4: K,V path — coalesced row-segment stores into d_out.
// ---------------------------------------------------------------------------
__global__ __launch_bounds__(256) void
gemm_qkv_kernel(const bf16_t* __restrict__ Wg, const bf16_t* __restrict__ xnT,
                bf16_t* __restrict__ qout, bf16_t* __restrict__ kvout) {
    const int bn = blockIdx.x, bm = blockIdx.y, b = blockIdx.z;
    const int t = threadIdx.x;
    const int w = t >> 6, ln = t & 63, quad = ln >> 4, l16 = ln & 15;
    const int wm = w >> 1, wn = w & 1;

    __shared__ __align__(16) __bf16 sAB[128 * LDC];
    __bf16* const sA = sAB;
    __bf16* const sB = sAB + 8192;

    f32x4 acc[4][4] = {};
    const bf16_t* Abase = Wg + (size_t)(bm * 128) * NC;
    const bf16_t* Bbase = xnT + (size_t)b * QSTRIDE + (size_t)(bn * 128) * NC;

    // R7 swizzle: permuted global k-granule, XOR ds_read (verified on HW)
    const int lrow = ln >> 3;
    const int lkc = ((ln & 7) ^ lrow) * 8;
    const int xr = l16 & 7;

    for (int kt = 0; kt < 8; ++kt) {
        const int k0 = kt * 64;
        #pragma unroll
        for (int i = 0; i < 4; ++i) {
            const int chunk = w * 4 + i;
            const int row = chunk * 8 + lrow;
            gload_lds16(Abase + (size_t)row * NC + k0 + lkc, &sA[chunk * 512]);
            gload_lds16(Bbase + (size_t)row * NC + k0 + lkc, &sB[chunk * 512]);
        }
        __syncthreads();
        #pragma unroll
        for (int ks = 0; ks < 2; ++ks) {
            bf8 af[4], bfr[4];
            const int kx = ((ks * 4 + quad) ^ xr) << 3;
            #pragma unroll
            for (int mi = 0; mi < 4; ++mi)
                af[mi] = *(const bf8*)&sA[(wm * 64 + mi * 16 + l16) * 64 + kx];
            #pragma unroll
            for (int ni = 0; ni < 4; ++ni)
                bfr[ni] = *(const bf8*)&sB[(wn * 64 + ni * 16 + l16) * 64 + kx];
            #pragma unroll
            for (int mi = 0; mi < 4; ++mi)
                #pragma unroll
                for (int ni = 0; ni < 4; ++ni)
                    acc[mi][ni] = __builtin_amdgcn_mfma_f32_16x16x32_bf16(
                        af[mi], bfr[ni], acc[mi][ni], 0, 0, 0);
        }
        __syncthreads();
    }

    const int p0 = bn * 128;
    if (bm < 4) {
        // ---- Q path: dump TRANSPOSED [token][chan], reg softmax, store ----
        #pragma unroll
        for (int mi = 0; mi < 4; ++mi)
            #pragma unroll
            for (int ni = 0; ni < 4; ++ni)
                #pragma unroll
                for (int r = 0; r < 4; ++r)
                    sAB[(wn * 64 + ni * 16 + l16) * LDC +
                        wm * 64 + mi * 16 + quad * 4 + r] = (__bf16)acc[mi][ni][r];
        __syncthreads();
        {
            // thread -> (token = t&127, head-half = t>>7); row held in regs
            __bf16* rp = &sAB[(t & 127) * LDC + (t >> 7) * 64];
            bf8 rr[8];
            #pragma unroll
            for (int gg = 0; gg < 8; ++gg) rr[gg] = *(const bf8*)&rp[gg * 8];
            float m = -1e30f;
            #pragma unroll
            for (int gg = 0; gg < 8; ++gg)
                #pragma unroll
                for (int j = 0; j < 8; ++j) m = fmaxf(m, (float)rr[gg][j]);
            float s = 0.f;
            #pragma unroll
            for (int gg = 0; gg < 8; ++gg)
                #pragma unroll
                for (int j = 0; j < 8; ++j) s += __expf((float)rr[gg][j] - m);
            const float inv = QSCALE / s;
            #pragma unroll
            for (int gg = 0; gg < 8; ++gg) {
                bf8 v;
                #pragma unroll
                for (int j = 0; j < 8; ++j)
                    v[j] = (__bf16)(__expf((float)rr[gg][j] - m) * inv);
                *(bf8*)&rp[gg * 8] = v;
            }
        }
        __syncthreads();
        bf16_t* qb = qout + (size_t)b * QSTRIDE;
        #pragma unroll
        for (int i = 0; i < 8; ++i) {
            int e = t + i * 256;               // 2048 = 128 tok x 16 c8
            int p = e >> 4, c8 = (e & 15) * 8;
            bf8 v = *(const bf8*)&sAB[p * LDC + c8];
            *(bf8*)&qb[(size_t)(p0 + p) * NC + bm * 128 + c8] = v;
        }
    } else {
        // ---- K/V path: normal dump + coalesced row-segment stores ---------
        {
            const int rbase = wm * 64 + quad * 4;
            const int cbase = wn * 64 + l16;
            #pragma unroll
            for (int mi = 0; mi < 4; ++mi)
                #pragma unroll
                for (int ni = 0; ni < 4; ++ni)
                    #pragma unroll
                    for (int r = 0; r < 4; ++r)
                        sAB[(rbase + mi * 16 + r) * LDC + cbase + ni * 16] =
                            (__bf16)acc[mi][ni][r];
        }
        __syncthreads();
        bf16_t* kvb = kvout + (size_t)b * KVSTRIDE;
        #pragma unroll
        for (int i = 0; i < 8; ++i) {
            int e = t + i * 256;
            int rr = e >> 4, seg = (e & 15) * 8;
            bf8 v = *(const bf8*)&sAB[rr * LDC + seg];
            *(bf8*)&kvb[(size_t)(bm * 128 + rr - 512) * NP + p0 + seg] = v;
        }
    }
}

// ---------------------------------------------------------------------------
// D: k-softmax stats per (b, channel) row. grid(512, 8) block 256.
// ---------------------------------------------------------------------------
__global__ __launch_bounds__(256) void
kstats_kernel(const bf16_t* __restrict__ kv, float* __restrict__ kmax,
              float* __restrict__ kinv) {
    const int oc = blockIdx.x, b = blockIdx.y;
    const int t = threadIdx.x, w = t >> 6, ln = t & 63;

    const bf16_t* row = kv + (size_t)b * KVSTRIDE + (size_t)oc * NP;
    float v[16];
    bf8 x0 = *(const bf8*)&row[t * 8];
    bf8 x1 = *(const bf8*)&row[2048 + t * 8];
    #pragma unroll
    for (int j = 0; j < 8; ++j) { v[j] = (float)x0[j]; v[8 + j] = (float)x1[j]; }

    float m = v[0];
    #pragma unroll
    for (int j = 1; j < 16; ++j) m = fmaxf(m, v[j]);
    #pragma unroll
    for (int off = 32; off > 0; off >>= 1) m = fmaxf(m, __shfl_down(m, off));
    __shared__ float sR[4];
    __shared__ float sS[4];
    if (ln == 0) sR[w] = m;
    __syncthreads();
    m = fmaxf(fmaxf(sR[0], sR[1]), fmaxf(sR[2], sR[3]));

    float s = 0.f;
    #pragma unroll
    for (int j = 0; j < 16; ++j) s += __expf(v[j] - m);
    #pragma unroll
    for (int off = 32; off > 0; off >>= 1) s += __shfl_down(s, off);
    if (ln == 0) sS[w] = s;
    __syncthreads();
    if (t == 0) {
        kmax[b * 512 + oc] = m;
        kinv[b * 512 + oc] = 1.0f / (sS[0] + sS[1] + sS[2] + sS[3]);
    }
}

// ---------------------------------------------------------------------------
// E: attnP[bh][ks][d][c] partials. grid(8, NKS=16, 8) = 1024 blocks
// (4/CU, 2x the latency-hiding waves of the 8-slice version). Each ks-slice
// covers 256 p (8 iters of 32 p). Wave-specialized over d; no atomics.
// Also zeroes ysq.
// ---------------------------------------------------------------------------
__global__ __launch_bounds__(256) void
attn_kernel(const bf16_t* __restrict__ kv, const float* __restrict__ kmax,
            float* __restrict__ attnP, float* __restrict__ ysq) {
    const int h = blockIdx.x, ks = blockIdx.y, b = blockIdx.z;
    const int t = threadIdx.x, w = t >> 6, ln = t & 63, quad = ln >> 4, l16 = ln & 15;

    const int zid = ((b * NKS + ks) * 8 + h) * 256 + t;
    if (zid < 8 * NP) ysq[zid] = 0.f;

    const bf16_t* Kb = kv + (size_t)b * KVSTRIDE + (size_t)(h * 64) * NP;
    const bf16_t* Vb = kv + (size_t)b * KVSTRIDE + (size_t)(512 + h * 64 + w * 16) * NP;

    float km[4];
    #pragma unroll
    for (int mi = 0; mi < 4; ++mi) km[mi] = kmax[b * 512 + h * 64 + mi * 16 + l16];

    f32x4 acc[4] = {};
    const int pbase = ks * 256 + quad * 8;
    #pragma unroll
    for (int it = 0; it < 8; ++it) {
        const int p0 = pbase + it * 32;
        bf8 bfr = *(const bf8*)&Vb[(size_t)l16 * NP + p0];
        #pragma unroll
        for (int mi = 0; mi < 4; ++mi) {
            bf8 kr = *(const bf8*)&Kb[(size_t)(mi * 16 + l16) * NP + p0];
            bf8 af;
            #pragma unroll
            for (int j = 0; j < 8; ++j)
                af[j] = (__bf16)__expf((float)kr[j] - km[mi]);
            acc[mi] = __builtin_amdgcn_mfma_f32_16x16x32_bf16(af, bfr, acc[mi], 0, 0, 0);
        }
    }

    float* outp = attnP + (((size_t)(b * 8 + h) * NKS + ks) << 12);
    #pragma unroll
    for (int mi = 0; mi < 4; ++mi) {
        float4 v;
        v.x = acc[mi][0]; v.y = acc[mi][1]; v.z = acc[mi][2]; v.w = acc[mi][3];
        *(float4*)&outp[(w * 16 + l16) * 64 + mi * 16 + quad * 4] = v;
    }
}

// ---------------------------------------------------------------------------
// E2 (chunk fallback only): attnF = (sum_ks attnP)*kinv -> bf16; zeroes ysq.
// ---------------------------------------------------------------------------
__global__ __launch_bounds__(256) void
attnsum_kernel(const float* __restrict__ attnP, const float* __restrict__ kinv,
               bf16_t* __restrict__ attnF, float* __restrict__ ysq) {
    const int gtid = (blockIdx.x * 4 + blockIdx.y) * 256 + threadIdx.x;
    if (gtid < 8 * NP) ysq[gtid] = 0.f;

    const int bh = blockIdx.x;
    const int e0 = blockIdx.y * 1024 + threadIdx.x * 4;
    const float* ap = attnP + ((size_t)bh << 16);   // NKS=16 slices of 4096
    float4 s = {0.f, 0.f, 0.f, 0.f};
    #pragma unroll
    for (int ks = 0; ks < NKS; ++ks) {
        float4 v = *(const float4*)&ap[(ks << 12) + e0];
        s.x += v.x; s.y += v.y; s.z += v.z; s.w += v.w;
    }
    const float* kvp = kinv + (bh >> 3) * 512 + (bh & 7) * 64;
    const int c = e0 & 63;
    ushort4 o;
    o.x = bfbits((__bf16)(s.x * kvp[c]));
    o.y = bfbits((__bf16)(s.y * kvp[c + 1]));
    o.z = bfbits((__bf16)(s.z * kvp[c + 2]));
    o.w = bfbits((__bf16)(s.w * kvp[c + 3]));
    *(ushort4*)&attnF[((size_t)bh << 12) + e0] = o;
}

// ---------------------------------------------------------------------------
// M: wmix — Wff[b][o][h*64+c] = sum_d Wf[o][h*64+d] * attnF[bh][d][c].
// grid(4, 8, 8) = (om, h, b), block 256. selfsum=1 (full): sums the 16
// L2-resident attnP partials with kinv folded. selfsum=0 (chunk): reads attnF.
// ---------------------------------------------------------------------------
__global__ __launch_bounds__(256) void
wmix_kernel(const bf16_t* __restrict__ Wf, const float* __restrict__ attnP,
            const float* __restrict__ kinv, const bf16_t* __restrict__ attnF,
            bf16_t* __restrict__ Wff, int selfsum) {
    const int om = blockIdx.x, h = blockIdx.y, b = blockIdx.z;
    const int t = threadIdx.x, w = t >> 6, ln = t & 63, quad = ln >> 4, l16 = ln & 15;

    __shared__ __bf16 sT[64][72];          // sT[c][d] = attnF[d][c]
    if (selfsum) {
        const float* ap = attnP + ((size_t)(b * 8 + h) << 16);
        const float* kvp = kinv + b * 512 + h * 64;
        #pragma unroll
        for (int i = 0; i < 2; ++i) {
            int e = t + i * 256;           // 512 jobs: d row, 8-c group
            int d = e >> 3, c8 = (e & 7) * 8;
            float s[8] = {};
            #pragma unroll
            for (int ks = 0; ks < NKS; ++ks) {
                const float* pp = &ap[(ks << 12) + d * 64 + c8];
                float4 v0 = *(const float4*)pp;
                float4 v1 = *(const float4*)(pp + 4);
                s[0] += v0.x; s[1] += v0.y; s[2] += v0.z; s[3] += v0.w;
                s[4] += v1.x; s[5] += v1.y; s[6] += v1.z; s[7] += v1.w;
            }
            #pragma unroll
            for (int j = 0; j < 8; ++j)
                sT[c8 + j][d] = (__bf16)(s[j] * kvp[c8 + j]);
        }
    } else {
        const bf16_t* aF = attnF + ((size_t)(b * 8 + h) << 12);
        #pragma unroll
        for (int i = 0; i < 2; ++i) {
            int e = t + i * 256;
            int d = e >> 3, c8 = (e & 7) * 8;
            bf8 v = *(const bf8*)&aF[d * 64 + c8];
            #pragma unroll
            for (int j = 0; j < 8; ++j) sT[c8 + j][d] = v[j];
        }
    }
    __syncthreads();

    const int obase = om * 128 + w * 32;
    f32x4 acc[2][4] = {};
    #pragma unroll
    for (int kk = 0; kk < 2; ++kk) {
        bf8 af[2], bfr[4];
        #pragma unroll
        for (int mi = 0; mi < 2; ++mi)
            af[mi] = *(const bf8*)&Wf[(size_t)(obase + mi * 16 + l16) * NC +
                                      h * 64 + kk * 32 + quad * 8];
        #pragma unroll
        for (int ni = 0; ni < 4; ++ni)
            bfr[ni] = *(const bf8*)&sT[ni * 16 + l16][kk * 32 + quad * 8];
        #pragma unroll
        for (int mi = 0; mi < 2; ++mi)
            #pragma unroll
            for (int ni = 0; ni < 4; ++ni)
                acc[mi][ni] = __builtin_amdgcn_mfma_f32_16x16x32_bf16(
                    af[mi], bfr[ni], acc[mi][ni], 0, 0, 0);
    }
    bf16_t* outp = Wff + ((size_t)b << 18);     // 512*512 per batch
    #pragma unroll
    for (int mi = 0; mi < 2; ++mi)
        #pragma unroll
        for (int ni = 0; ni < 4; ++ni)
            #pragma unroll
            for (int r = 0; r < 4; ++r) {
                int o = obase + mi * 16 + quad * 4 + r;
                int c = ni * 16 + l16;
                outp[(size_t)o * NC + h * 64 + c] = (__bf16)acc[mi][ni][r];
            }
}

// ---------------------------------------------------------------------------
// G: FFN GEMM. grid(32, 4, 8) block 256. A = Wff[b], B = qsm [p][c].
// ybf=1 (full): bf16 y into ws (dead xnT region), ysq from rounded bf16.
// ybf=0 (chunk): fp32 y direct into d_out, ysq from fp32, two-half C-write.
// ---------------------------------------------------------------------------
__global__ __launch_bounds__(256) void
gemm_ffn_kernel(const bf16_t* __restrict__ Wff, const bf16_t* __restrict__ qsm,
                const float* __restrict__ bias, float* __restrict__ outf,
                bf16_t* __restrict__ ybf16, float* __restrict__ ysq, int ybf) {
    const int bn = blockIdx.x, bm = blockIdx.y, b = blockIdx.z;
    const int t = threadIdx.x;
    const int w = t >> 6, ln = t & 63, quad = ln >> 4, l16 = ln & 15;
    const int wm = w >> 1, wn = w & 1;

    __shared__ __align__(16) __bf16 sAB[128 * LDC];
    __bf16* const sA = sAB;
    __bf16* const sB = sAB + 8192;

    f32x4 acc[4][4] = {};
    const bf16_t* Abase = Wff + ((size_t)b << 18) + (size_t)(bm * 128) * NC;
    const bf16_t* Bbase = qsm + (size_t)b * QSTRIDE + (size_t)(bn * 128) * NC;

    const int lrow = ln >> 3;
    const int lkc = ((ln & 7) ^ lrow) * 8;
    const int xr = l16 & 7;

    for (int kt = 0; kt < 8; ++kt) {
        const int k0 = kt * 64;
        #pragma unroll
        for (int i = 0; i < 4; ++i) {
            const int chunk = w * 4 + i;
            const int row = chunk * 8 + lrow;
            gload_lds16(Abase + (size_t)row * NC + k0 + lkc, &sA[chunk * 512]);
            gload_lds16(Bbase + (size_t)row * NC + k0 + lkc, &sB[chunk * 512]);
        }
        __syncthreads();
        #pragma unroll
        for (int ks = 0; ks < 2; ++ks) {
            bf8 af[4], bfr[4];
            const int kx = ((ks * 4 + quad) ^ xr) << 3;
            #pragma unroll
            for (int mi = 0; mi < 4; ++mi)
                af[mi] = *(const bf8*)&sA[(wm * 64 + mi * 16 + l16) * 64 + kx];
            #pragma unroll
            for (int ni = 0; ni < 4; ++ni)
                bfr[ni] = *(const bf8*)&sB[(wn * 64 + ni * 16 + l16) * 64 + kx];
            #pragma unroll
            for (int mi = 0; mi < 4; ++mi)
                #pragma unroll
                for (int ni = 0; ni < 4; ++ni)
                    acc[mi][ni] = __builtin_amdgcn_mfma_f32_16x16x32_bf16(
                        af[mi], bfr[ni], acc[mi][ni], 0, 0, 0);
        }
        __syncthreads();
    }

    float* sq = ysq + (size_t)b * NP;
    const int p0 = bn * 128;
    const int rbase = wm * 64 + quad * 4;

    if (ybf) {
        // bf16 y path (R7-consistent): ysq from rounded bf16, LDS C-tile
        #pragma unroll
        for (int ni = 0; ni < 4; ++ni) {
            const int col = p0 + wn * 64 + ni * 16 + l16;
            float colsq = 0.f;
            #pragma unroll
            for (int mi = 0; mi < 4; ++mi) {
                #pragma unroll
                for (int r = 0; r < 4; ++r) {
                    const int row = bm * 128 + rbase + mi * 16 + r;
                    __bf16 vb = (__bf16)(acc[mi][ni][r] + bias[row]);
                    sAB[(rbase + mi * 16 + r) * LDC + wn * 64 + ni * 16 + l16] = vb;
                    float vf = (float)vb;
                    colsq += vf * vf;
                }
            }
            colsq += __shfl_xor(colsq, 16);
            colsq += __shfl_xor(colsq, 32);
            if (quad == 0) atomicAdd(&sq[col], colsq);
        }
        __syncthreads();
        bf16_t* yb = ybf16 + (size_t)b * QSTRIDE;
        #pragma unroll
        for (int i = 0; i < 8; ++i) {
            int e = t + i * 256;
            int rr = e >> 4, seg = (e & 15) * 8;
            bf8 v = *(const bf8*)&sAB[rr * LDC + seg];
            *(bf8*)&yb[(size_t)(bm * 128 + rr) * NP + p0 + seg] = v;
        }
    } else {
        // fp32 y path (chunk fallback, R9)
        #pragma unroll
        for (int ni = 0; ni < 4; ++ni) {
            const int col = p0 + wn * 64 + ni * 16 + l16;
            float colsq = 0.f;
            #pragma unroll
            for (int mi = 0; mi < 4; ++mi)
                #pragma unroll
                for (int r = 0; r < 4; ++r) {
                    float vf = acc[mi][ni][r] + bias[bm * 128 + rbase + mi * 16 + r];
                    colsq += vf * vf;
                }
            colsq += __shfl_xor(colsq, 16);
            colsq += __shfl_xor(colsq, 32);
            if (quad == 0) atomicAdd(&sq[col], colsq);
        }
        float* sF = (float*)sAB;                    // [64][136] f32 = 34816 B
        float* ob = outf + (size_t)b * QSTRIDE;
        #pragma unroll
        for (int half = 0; half < 2; ++half) {
            __syncthreads();
            if (wm == half) {
                #pragma unroll
                for (int mi = 0; mi < 4; ++mi)
                    #pragma unroll
                    for (int ni = 0; ni < 4; ++ni)
                        #pragma unroll
                        for (int r = 0; r < 4; ++r)
                            sF[(quad * 4 + mi * 16 + r) * 136 + wn * 64 + ni * 16 + l16] =
                                acc[mi][ni][r] +
                                bias[bm * 128 + half * 64 + quad * 4 + mi * 16 + r];
            }
            __syncthreads();
            #pragma unroll
            for (int i = 0; i < 8; ++i) {
                int e = t + i * 256;
                int rr = e >> 5, c4 = (e & 31) * 4;
                float4 v = *(const float4*)&sF[rr * 136 + c4];
                *(float4*)&ob[(size_t)(bm * 128 + half * 64 + rr) * NP + p0 + c4] = v;
            }
        }
    }
}

// ---------------------------------------------------------------------------
// H: final. ybf=1: out = ybf16*inv*g2*sqrtC + x (write-only out).
//          ybf=0: in-place on fp32 out (chunk fallback).
// grid(1024, 8) block 256.
// ---------------------------------------------------------------------------
__global__ __launch_bounds__(256) void
final_kernel(float* __restrict__ out, const bf16_t* __restrict__ ybf16,
             const float* __restrict__ ysq, const float* __restrict__ g2,
             const float* __restrict__ x, int ybf) {
    const int b = blockIdx.y;
    int idx = blockIdx.x * 256 + threadIdx.x;
    int o = idx >> 9;
    int p8 = (idx & 511) * 8;
    float* ob = out + (size_t)b * QSTRIDE;
    const float* xb = x + (size_t)b * QSTRIDE;
    const float* sq = ysq + (size_t)b * NP;

    float gv = g2[o] * SQRTC;
    float4 a = *(const float4*)&xb[(size_t)o * NP + p8];
    float4 b2 = *(const float4*)&xb[(size_t)o * NP + p8 + 4];
    float inb[8];
    #pragma unroll
    for (int j = 0; j < 8; ++j)
        inb[j] = 1.0f / fmaxf(sqrtf(sq[p8 + j]), 1e-12f);

    float y[8];
    if (ybf) {
        const bf16_t* yb = ybf16 + (size_t)b * QSTRIDE;
        bf8 yv = *(const bf8*)&yb[(size_t)o * NP + p8];
        #pragma unroll
        for (int j = 0; j < 8; ++j) y[j] = (float)yv[j];
    } else {
        float4 y0 = *(const float4*)&ob[(size_t)o * NP + p8];
        float4 y1 = *(const float4*)&ob[(size_t)o * NP + p8 + 4];
        y[0] = y0.x; y[1] = y0.y; y[2] = y0.z; y[3] = y0.w;
        y[4] = y1.x; y[5] = y1.y; y[6] = y1.z; y[7] = y1.w;
    }

    float4 r0, r1;
    r0.x = y[0] * inb[0] * gv + a.x;
    r0.y = y[1] * inb[1] * gv + a.y;
    r0.z = y[2] * inb[2] * gv + a.z;
    r0.w = y[3] * inb[3] * gv + a.w;
    r1.x = y[4] * inb[4] * gv + b2.x;
    r1.y = y[5] * inb[5] * gv + b2.y;
    r1.z = y[6] * inb[6] * gv + b2.z;
    r1.w = y[7] * inb[7] * gv + b2.w;
    *(float4*)&ob[(size_t)o * NP + p8] = r0;
    *(float4*)&ob[(size_t)o * NP + p8 + 4] = r1;
}

// ---------------------------------------------------------------------------
extern "C" void kernel_launch(void* const* d_in, const int* in_sizes, int n_in,
                              void* d_out, int out_size, void* d_ws, size_t ws_size,
                              hipStream_t stream) {
    const float* x     = (const float*)d_in[0];
    const float* g     = (const float*)d_in[1];
    const float* qkv_w = (const float*)d_in[2];
    const float* ffn_w = (const float*)d_in[3];
    const float* ffn_b = (const float*)d_in[4];
    const float* ffn_g = (const float*)d_in[5];
    float* out = (float*)d_out;
    bf16_t* kv = (bf16_t*)d_out;     // K,V bf16; later Wff (full) / fp32 y

    const size_t FULL_BYTES =
        (8 * QSTRIDE + 8 * QSTRIDE + 786432 + 262144) * sizeof(bf16_t) +
        (8 * 512 + 8 * 512 + 8 * (size_t)NP) * sizeof(float);
    const bool full = ws_size >= FULL_BYTES;

    bf16_t* q    = (bf16_t*)d_ws;                    // qsm, [p][c] per batch
    bf16_t* xnT  = q + 8 * QSTRIDE;                  // 8 or 2 batches
    bf16_t* Wg   = xnT + (full ? 8 : 2) * QSTRIDE;   // 786432 bf16
    float*  attnP = (float*)xnT;                     // 16.8 MB (xnT dead)
    bf16_t* y16  = xnT;                              // full: bf16 y (attnP dead)
    bf16_t* attnF = Wg;                              // chunk only (Wg dead)
    bf16_t* WffC = xnT;                              // chunk: Wff (attnP dead)
    bf16_t* WffF = kv;                               // full: Wff in d_out (K dead)
    bf16_t* Wf   = Wg + 786432;                      // 262144 bf16
    float*  kmax = (float*)(Wf + 262144);            // 8*512 f32
    float*  kinv = kmax + 8 * 512;                   // 8*512 f32
    float*  ysq  = kinv + 8 * 512;                   // 8*4096 f32

    if (full) {
        norm_transpose_kernel<<<dim3(128, 8), 512, 0, stream>>>(
            x, xnT, qkv_w, g, ffn_w, Wg, Wf, 1);
        gemm_qkv_kernel<<<dim3(32, 12, 8), 256, 0, stream>>>(Wg, xnT, q, kv);
        kstats_kernel<<<dim3(512, 8), 256, 0, stream>>>(kv, kmax, kinv);
        attn_kernel<<<dim3(8, NKS, 8), 256, 0, stream>>>(kv, kmax, attnP, ysq);
        wmix_kernel<<<dim3(4, 8, 8), 256, 0, stream>>>(
            Wf, attnP, kinv, nullptr, WffF, 1);
        gemm_ffn_kernel<<<dim3(32, 4, 8), 256, 0, stream>>>(
            WffF, q, ffn_b, nullptr, y16, ysq, 1);
        final_kernel<<<dim3(1024, 8), 256, 0, stream>>>(
            out, y16, ysq, ffn_g, x, 1);
    } else {
        wconv_kernel<<<dim3(1024), 256, 0, stream>>>(qkv_w, g, ffn_w, Wg, Wf);
        for (int c = 0; c < 4; ++c) {
            norm_transpose_kernel<<<dim3(128, 2), 512, 0, stream>>>(
                x + (size_t)(2 * c) * QSTRIDE, xnT,
                qkv_w, g, ffn_w, Wg, Wf, 0);
            gemm_qkv_kernel<<<dim3(32, 12, 2), 256, 0, stream>>>(
                Wg, xnT, q + (size_t)(2 * c) * QSTRIDE,
                kv + (size_t)(2 * c) * KVSTRIDE);
        }
        kstats_kernel<<<dim3(512, 8), 256, 0, stream>>>(kv, kmax, kinv);
        attn_kernel<<<dim3(8, NKS, 8), 256, 0, stream>>>(kv, kmax, attnP, ysq);
        attnsum_kernel<<<dim3(64, 4), 256, 0, stream>>>(attnP, kinv, attnF, ysq);
        wmix_kernel<<<dim3(4, 8, 8), 256, 0, stream>>>(
            Wf, attnP, kinv, attnF, WffC, 0);
        gemm_ffn_kernel<<<dim3(32, 4, 8), 256, 0, stream>>>(
            WffC, q, ffn_b, out, nullptr, ysq, 0);
        final_kernel<<<dim3(1024, 8), 256, 0, stream>>>(
            out, nullptr, ysq, ffn_g, x, 0);
    }
}

// Round 13
// 296.442 us; speedup vs baseline: 1.0200x; 1.0200x over previous
//
#include <hip/hip_runtime.h>

// ---------------------------------------------------------------------------
// MultiHeadsLinearAttention  (B=8, C=512, HEADS=8, CH=64, H=W=64 -> N=4096)
// Inputs fp32, output fp32. Compute: bf16 MFMA, fp32 accumulation.
//
// Dataflow (outgemm eliminated by associativity, R8):
//   y = Wf @ (qsm @ attnF)  ==  (Wf_h @ attnF_h per head) @ qsm = Wff_b @ qsm
// Stages (full-ws mode):
//  T : norm+transpose (+fused weight convert); xnT[p][c] bf16
//  C : QKV GEMM (128x128, BK=64, gload_lds + R7 source-permutation swizzle);
//      Q path fuses q-softmax on fp32 acc (register-resident), qsm [p][c];
//      K,V -> d_out
//  D : k-softmax stats (kmax,kinv)
//  E : attnP partials, NKS=8 p-slices (R13: reverted from 16 — R12 measured
//      +8us: doubled attnP traffic outweighed the occupancy gain; attn's
//      loads are L2-resident post-qkv, already latency-covered at 8 waves/CU)
//  M : wmix self-sums 8 attnP partials (L2-hot), folds kinv, computes
//      Wff[b][o][h*64+c] -> d_out base (K/V dead)
//  G : FFN GEMM y = ffn_b + Wff_b @ qsm -> bf16 y into dead xnT region;
//      ysq from bf16-rounded y
//  H : final: out = y*inv(||col||)*g2*sqrtC + x -> d_out (write-only)
// Chunk-ws fallback keeps the R9 pipeline (flagged paths).
//
// R7: swizzle pairing verified on HW (bank conflicts 19.3M -> 393K).
// R12 lesson: NKS=16 regressed (+8us); reverted. qkv 82us = m97-structure
// ceiling at K=512 (MfmaUtil 25%, HBM 22% — structure-bound). The 8-phase
// 256^2 port is the only documented lever past it but requires race-screen
// (m152) unavailable headless — deliberately declined.
// ---------------------------------------------------------------------------

typedef __bf16 bf16_t;
typedef __bf16 bf8 __attribute__((ext_vector_type(8)));
typedef float f32x4 __attribute__((ext_vector_type(4)));

#define NC 512
#define NP 4096
#define SQRTC 22.62741699796952f
#define QSCALE 0.125f
#define QSTRIDE  ((size_t)NC * NP)      // 2097152  per-batch 512-row elems
#define KVSTRIDE ((size_t)1024 * NP)    // 4194304  per-batch kv elems (d_out)
#define LDC 136                          // epilogue C-tile stride (bank-spread)
#define NKS 8                            // attn p-slices (R13: reverted 16->8)

__device__ inline unsigned short bfbits(__bf16 h) {
    return __builtin_bit_cast(unsigned short, h);
}

// async global->LDS, 16B per lane. LDS dest wave-uniform base + lane*16.
__device__ __forceinline__ void gload_lds16(const bf16_t* g, __bf16* l) {
    __builtin_amdgcn_global_load_lds(
        (const __attribute__((address_space(1))) void*)g,
        (__attribute__((address_space(3))) void*)l, 16, 0, 0);
}

// ---------------------------------------------------------------------------
// W (chunk fallback only): both weight converts.
// ---------------------------------------------------------------------------
__global__ __launch_bounds__(256) void
wconv_kernel(const float* __restrict__ qkv_w, const float* __restrict__ g,
             const float* __restrict__ ffn_w, bf16_t* __restrict__ Wg,
             bf16_t* __restrict__ Wf) {
    const int bx = blockIdx.x;
    if (bx < 768) {
        int i0 = (bx * 256 + threadIdx.x) * 4;
        float4 wv = *(const float4*)&qkv_w[i0];
        const float4 gv = *(const float4*)&g[i0 & 511];
        ushort4 o;
        o.x = bfbits((__bf16)(wv.x * gv.x));
        o.y = bfbits((__bf16)(wv.y * gv.y));
        o.z = bfbits((__bf16)(wv.z * gv.z));
        o.w = bfbits((__bf16)(wv.w * gv.w));
        *(ushort4*)&Wg[i0] = o;
    } else {
        int i0 = ((bx - 768) * 256 + threadIdx.x) * 4;
        float4 wv = *(const float4*)&ffn_w[i0];
        ushort4 o;
        o.x = bfbits((__bf16)wv.x);
        o.y = bfbits((__bf16)wv.y);
        o.z = bfbits((__bf16)wv.z);
        o.w = bfbits((__bf16)wv.w);
        *(ushort4*)&Wf[i0] = o;
    }
}

// ---------------------------------------------------------------------------
// T: norm + transpose (+ optional fused weight convert in blocks bid<512).
// grid(128, nb) block 512. xnT[p][c] = x[c][p] * sqrtC/max(||x[:,p]||,eps)
// ---------------------------------------------------------------------------
__global__ __launch_bounds__(512) void
norm_transpose_kernel(const float* __restrict__ x, bf16_t* __restrict__ xnT,
                      const float* __restrict__ qkv_w, const float* __restrict__ g,
                      const float* __restrict__ ffn_w, bf16_t* __restrict__ Wg,
                      bf16_t* __restrict__ Wf, int doW) {
    const int bl = blockIdx.y;
    const int p0 = blockIdx.x * 32;
    const int t = threadIdx.x;

    if (doW) {                            // fused weight convert (full mode)
        const int bid = blockIdx.y * 128 + blockIdx.x;
        if (bid < 512) {
            int i0 = bid * 2048 + t * 4;  // blocks 0..383 qkv, 384..511 ffn
            if (i0 < 786432) {
                float4 wv = *(const float4*)&qkv_w[i0];
                const float4 gv = *(const float4*)&g[i0 & 511];
                ushort4 o;
                o.x = bfbits((__bf16)(wv.x * gv.x));
                o.y = bfbits((__bf16)(wv.y * gv.y));
                o.z = bfbits((__bf16)(wv.z * gv.z));
                o.w = bfbits((__bf16)(wv.w * gv.w));
                *(ushort4*)&Wg[i0] = o;
            } else {
                int j0 = i0 - 786432;
                float4 wv = *(const float4*)&ffn_w[j0];
                ushort4 o;
                o.x = bfbits((__bf16)wv.x);
                o.y = bfbits((__bf16)wv.y);
                o.z = bfbits((__bf16)wv.z);
                o.w = bfbits((__bf16)wv.w);
                *(ushort4*)&Wf[j0] = o;
            }
        }
    }

    const float* xb = x + (size_t)bl * QSTRIDE;
    bf16_t* ob = xnT + (size_t)bl * QSTRIDE;

    // pass 1: sumsq, float4 coalesced + shfl_xor tree
    const int cg = t & 7, r0 = t >> 3;
    f32x4 ss = {0.f, 0.f, 0.f, 0.f};
    #pragma unroll
    for (int k = 0; k < 8; ++k) {
        const int c = r0 + k * 64;
        float4 v = *(const float4*)&xb[(size_t)c * NP + p0 + cg * 4];
        ss.x += v.x * v.x; ss.y += v.y * v.y;
        ss.z += v.z * v.z; ss.w += v.w * v.w;
    }
    #pragma unroll
    for (int m = 8; m <= 32; m <<= 1) {
        ss.x += __shfl_xor(ss.x, m); ss.y += __shfl_xor(ss.y, m);
        ss.z += __shfl_xor(ss.z, m); ss.w += __shfl_xor(ss.w, m);
    }
    __shared__ float sP[8][34];
    __shared__ float sInv[32];
    const int w = t >> 6;
    if ((t & 63) < 8) {
        const int p = (t & 7) * 4;
        sP[w][p] = ss.x; sP[w][p + 1] = ss.y;
        sP[w][p + 2] = ss.z; sP[w][p + 3] = ss.w;
    }
    __syncthreads();
    if (t < 32) {
        float tot = 0.f;
        #pragma unroll
        for (int j = 0; j < 8; ++j) tot += sP[j][t];
        sInv[t] = SQRTC / fmaxf(sqrtf(tot), 1e-12f);
    }
    __syncthreads();

    // pass 2: 128-c x 32-p chunks through LDS transpose, float4 loads
    __shared__ __bf16 sT[128][41];
    for (int cc = 0; cc < 512; cc += 128) {
        #pragma unroll
        for (int j = 0; j < 2; ++j) {
            int idx = t + j * 512;               // [0,1024): 128 cr x 8 pg
            int cr = idx >> 3, pg = idx & 7;
            float4 v = *(const float4*)&xb[(size_t)(cc + cr) * NP + p0 + pg * 4];
            sT[cr][pg * 4 + 0] = (__bf16)(v.x * sInv[pg * 4 + 0]);
            sT[cr][pg * 4 + 1] = (__bf16)(v.y * sInv[pg * 4 + 1]);
            sT[cr][pg * 4 + 2] = (__bf16)(v.z * sInv[pg * 4 + 2]);
            sT[cr][pg * 4 + 3] = (__bf16)(v.w * sInv[pg * 4 + 3]);
        }
        __syncthreads();
        {
            int p = t >> 4, c8 = (t & 15) * 8;
            bf8 v;
            #pragma unroll
            for (int q = 0; q < 8; ++q) v[q] = sT[c8 + q][p];
            *(bf8*)&ob[(size_t)(p0 + p) * NC + cc + c8] = v;
        }
        __syncthreads();
    }
}

// ---------------------------------------------------------------------------
// C: QKV GEMM. grid(32, 12, nb) block 256.
// bm<4: Q path — register-resident softmax epilogue, store qsm [p][c].
// bm>=4: K,V path — coalesced row-segment stores into d_out.
// ---------------------------------------------------------------------------
__global__ __launch_bounds__(256) void
gemm_qkv_kernel(const bf16_t* __restrict__ Wg, const bf16_t* __restrict__ xnT,
                bf16_t* __restrict__ qout, bf16_t* __restrict__ kvout) {
    const int bn = blockIdx.x, bm = blockIdx.y, b = blockIdx.z;
    const int t = threadIdx.x;
    const int w = t >> 6, ln = t & 63, quad = ln >> 4, l16 = ln & 15;
    const int wm = w >> 1, wn = w & 1;

    __shared__ __align__(16) __bf16 sAB[128 * LDC];
    __bf16* const sA = sAB;
    __bf16* const sB = sAB + 8192;

    f32x4 acc[4][4] = {};
    const bf16_t* Abase = Wg + (size_t)(bm * 128) * NC;
    const bf16_t* Bbase = xnT + (size_t)b * QSTRIDE + (size_t)(bn * 128) * NC;

    // R7 swizzle: permuted global k-granule, XOR ds_read (verified on HW)
    const int lrow = ln >> 3;
    const int lkc = ((ln & 7) ^ lrow) * 8;
    const int xr = l16 & 7;

    for (int kt = 0; kt < 8; ++kt) {
        const int k0 = kt * 64;
        #pragma unroll
        for (int i = 0; i < 4; ++i) {
            const int chunk = w * 4 + i;
            const int row = chunk * 8 + lrow;
            gload_lds16(Abase + (size_t)row * NC + k0 + lkc, &sA[chunk * 512]);
            gload_lds16(Bbase + (size_t)row * NC + k0 + lkc, &sB[chunk * 512]);
        }
        __syncthreads();
        #pragma unroll
        for (int ks = 0; ks < 2; ++ks) {
            bf8 af[4], bfr[4];
            const int kx = ((ks * 4 + quad) ^ xr) << 3;
            #pragma unroll
            for (int mi = 0; mi < 4; ++mi)
                af[mi] = *(const bf8*)&sA[(wm * 64 + mi * 16 + l16) * 64 + kx];
            #pragma unroll
            for (int ni = 0; ni < 4; ++ni)
                bfr[ni] = *(const bf8*)&sB[(wn * 64 + ni * 16 + l16) * 64 + kx];
            #pragma unroll
            for (int mi = 0; mi < 4; ++mi)
                #pragma unroll
                for (int ni = 0; ni < 4; ++ni)
                    acc[mi][ni] = __builtin_amdgcn_mfma_f32_16x16x32_bf16(
                        af[mi], bfr[ni], acc[mi][ni], 0, 0, 0);
        }
        __syncthreads();
    }

    const int p0 = bn * 128;
    if (bm < 4) {
        // ---- Q path: dump TRANSPOSED [token][chan], reg softmax, store ----
        #pragma unroll
        for (int mi = 0; mi < 4; ++mi)
            #pragma unroll
            for (int ni = 0; ni < 4; ++ni)
                #pragma unroll
                for (int r = 0; r < 4; ++r)
                    sAB[(wn * 64 + ni * 16 + l16) * LDC +
                        wm * 64 + mi * 16 + quad * 4 + r] = (__bf16)acc[mi][ni][r];
        __syncthreads();
        {
            // thread -> (token = t&127, head-half = t>>7); row held in regs
            __bf16* rp = &sAB[(t & 127) * LDC + (t >> 7) * 64];
            bf8 rr[8];
            #pragma unroll
            for (int gg = 0; gg < 8; ++gg) rr[gg] = *(const bf8*)&rp[gg * 8];
            float m = -1e30f;
            #pragma unroll
            for (int gg = 0; gg < 8; ++gg)
                #pragma unroll
                for (int j = 0; j < 8; ++j) m = fmaxf(m, (float)rr[gg][j]);
            float s = 0.f;
            #pragma unroll
            for (int gg = 0; gg < 8; ++gg)
                #pragma unroll
                for (int j = 0; j < 8; ++j) s += __expf((float)rr[gg][j] - m);
            const float inv = QSCALE / s;
            #pragma unroll
            for (int gg = 0; gg < 8; ++gg) {
                bf8 v;
                #pragma unroll
                for (int j = 0; j < 8; ++j)
                    v[j] = (__bf16)(__expf((float)rr[gg][j] - m) * inv);
                *(bf8*)&rp[gg * 8] = v;
            }
        }
        __syncthreads();
        bf16_t* qb = qout + (size_t)b * QSTRIDE;
        #pragma unroll
        for (int i = 0; i < 8; ++i) {
            int e = t + i * 256;               // 2048 = 128 tok x 16 c8
            int p = e >> 4, c8 = (e & 15) * 8;
            bf8 v = *(const bf8*)&sAB[p * LDC + c8];
            *(bf8*)&qb[(size_t)(p0 + p) * NC + bm * 128 + c8] = v;
        }
    } else {
        // ---- K/V path: normal dump + coalesced row-segment stores ---------
        {
            const int rbase = wm * 64 + quad * 4;
            const int cbase = wn * 64 + l16;
            #pragma unroll
            for (int mi = 0; mi < 4; ++mi)
                #pragma unroll
                for (int ni = 0; ni < 4; ++ni)
                    #pragma unroll
                    for (int r = 0; r < 4; ++r)
                        sAB[(rbase + mi * 16 + r) * LDC + cbase + ni * 16] =
                            (__bf16)acc[mi][ni][r];
        }
        __syncthreads();
        bf16_t* kvb = kvout + (size_t)b * KVSTRIDE;
        #pragma unroll
        for (int i = 0; i < 8; ++i) {
            int e = t + i * 256;
            int rr = e >> 4, seg = (e & 15) * 8;
            bf8 v = *(const bf8*)&sAB[rr * LDC + seg];
            *(bf8*)&kvb[(size_t)(bm * 128 + rr - 512) * NP + p0 + seg] = v;
        }
    }
}

// ---------------------------------------------------------------------------
// D: k-softmax stats per (b, channel) row. grid(512, 8) block 256.
// ---------------------------------------------------------------------------
__global__ __launch_bounds__(256) void
kstats_kernel(const bf16_t* __restrict__ kv, float* __restrict__ kmax,
              float* __restrict__ kinv) {
    const int oc = blockIdx.x, b = blockIdx.y;
    const int t = threadIdx.x, w = t >> 6, ln = t & 63;

    const bf16_t* row = kv + (size_t)b * KVSTRIDE + (size_t)oc * NP;
    float v[16];
    bf8 x0 = *(const bf8*)&row[t * 8];
    bf8 x1 = *(const bf8*)&row[2048 + t * 8];
    #pragma unroll
    for (int j = 0; j < 8; ++j) { v[j] = (float)x0[j]; v[8 + j] = (float)x1[j]; }

    float m = v[0];
    #pragma unroll
    for (int j = 1; j < 16; ++j) m = fmaxf(m, v[j]);
    #pragma unroll
    for (int off = 32; off > 0; off >>= 1) m = fmaxf(m, __shfl_down(m, off));
    __shared__ float sR[4];
    __shared__ float sS[4];
    if (ln == 0) sR[w] = m;
    __syncthreads();
    m = fmaxf(fmaxf(sR[0], sR[1]), fmaxf(sR[2], sR[3]));

    float s = 0.f;
    #pragma unroll
    for (int j = 0; j < 16; ++j) s += __expf(v[j] - m);
    #pragma unroll
    for (int off = 32; off > 0; off >>= 1) s += __shfl_down(s, off);
    if (ln == 0) sS[w] = s;
    __syncthreads();
    if (t == 0) {
        kmax[b * 512 + oc] = m;
        kinv[b * 512 + oc] = 1.0f / (sS[0] + sS[1] + sS[2] + sS[3]);
    }
}

// ---------------------------------------------------------------------------
// E: attnP[bh][ks][d][c] partials. grid(8, NKS=8, 8) block 256. Each ks-slice
// covers 512 p (16 iters of 32 p). Wave-specialized over d; no atomics.
// Also zeroes ysq.
// ---------------------------------------------------------------------------
__global__ __launch_bounds__(256) void
attn_kernel(const bf16_t* __restrict__ kv, const float* __restrict__ kmax,
            float* __restrict__ attnP, float* __restrict__ ysq) {
    const int h = blockIdx.x, ks = blockIdx.y, b = blockIdx.z;
    const int t = threadIdx.x, w = t >> 6, ln = t & 63, quad = ln >> 4, l16 = ln & 15;

    const int zid = ((b * NKS + ks) * 8 + h) * 256 + t;
    if (zid < 8 * NP) ysq[zid] = 0.f;

    const bf16_t* Kb = kv + (size_t)b * KVSTRIDE + (size_t)(h * 64) * NP;
    const bf16_t* Vb = kv + (size_t)b * KVSTRIDE + (size_t)(512 + h * 64 + w * 16) * NP;

    float km[4];
    #pragma unroll
    for (int mi = 0; mi < 4; ++mi) km[mi] = kmax[b * 512 + h * 64 + mi * 16 + l16];

    f32x4 acc[4] = {};
    const int pbase = ks * 512 + quad * 8;
    #pragma unroll 4
    for (int it = 0; it < 16; ++it) {
        const int p0 = pbase + it * 32;
        bf8 bfr = *(const bf8*)&Vb[(size_t)l16 * NP + p0];
        #pragma unroll
        for (int mi = 0; mi < 4; ++mi) {
            bf8 kr = *(const bf8*)&Kb[(size_t)(mi * 16 + l16) * NP + p0];
            bf8 af;
            #pragma unroll
            for (int j = 0; j < 8; ++j)
                af[j] = (__bf16)__expf((float)kr[j] - km[mi]);
            acc[mi] = __builtin_amdgcn_mfma_f32_16x16x32_bf16(af, bfr, acc[mi], 0, 0, 0);
        }
    }

    float* outp = attnP + (((size_t)(b * 8 + h) * NKS + ks) << 12);
    #pragma unroll
    for (int mi = 0; mi < 4; ++mi) {
        float4 v;
        v.x = acc[mi][0]; v.y = acc[mi][1]; v.z = acc[mi][2]; v.w = acc[mi][3];
        *(float4*)&outp[(w * 16 + l16) * 64 + mi * 16 + quad * 4] = v;
    }
}

// ---------------------------------------------------------------------------
// E2 (chunk fallback only): attnF = (sum_ks attnP)*kinv -> bf16; zeroes ysq.
// ---------------------------------------------------------------------------
__global__ __launch_bounds__(256) void
attnsum_kernel(const float* __restrict__ attnP, const float* __restrict__ kinv,
               bf16_t* __restrict__ attnF, float* __restrict__ ysq) {
    const int gtid = (blockIdx.x * 4 + blockIdx.y) * 256 + threadIdx.x;
    if (gtid < 8 * NP) ysq[gtid] = 0.f;

    const int bh = blockIdx.x;
    const int e0 = blockIdx.y * 1024 + threadIdx.x * 4;
    const float* ap = attnP + ((size_t)bh << 15);   // NKS=8 slices of 4096
    float4 s = {0.f, 0.f, 0.f, 0.f};
    #pragma unroll
    for (int ks = 0; ks < NKS; ++ks) {
        float4 v = *(const float4*)&ap[(ks << 12) + e0];
        s.x += v.x; s.y += v.y; s.z += v.z; s.w += v.w;
    }
    const float* kvp = kinv + (bh >> 3) * 512 + (bh & 7) * 64;
    const int c = e0 & 63;
    ushort4 o;
    o.x = bfbits((__bf16)(s.x * kvp[c]));
    o.y = bfbits((__bf16)(s.y * kvp[c + 1]));
    o.z = bfbits((__bf16)(s.z * kvp[c + 2]));
    o.w = bfbits((__bf16)(s.w * kvp[c + 3]));
    *(ushort4*)&attnF[((size_t)bh << 12) + e0] = o;
}

// ---------------------------------------------------------------------------
// M: wmix — Wff[b][o][h*64+c] = sum_d Wf[o][h*64+d] * attnF[bh][d][c].
// grid(4, 8, 8) = (om, h, b), block 256. selfsum=1 (full): sums the 8
// L2-resident attnP partials with kinv folded. selfsum=0 (chunk): reads attnF.
// ---------------------------------------------------------------------------
__global__ __launch_bounds__(256) void
wmix_kernel(const bf16_t* __restrict__ Wf, const float* __restrict__ attnP,
            const float* __restrict__ kinv, const bf16_t* __restrict__ attnF,
            bf16_t* __restrict__ Wff, int selfsum) {
    const int om = blockIdx.x, h = blockIdx.y, b = blockIdx.z;
    const int t = threadIdx.x, w = t >> 6, ln = t & 63, quad = ln >> 4, l16 = ln & 15;

    __shared__ __bf16 sT[64][72];          // sT[c][d] = attnF[d][c]
    if (selfsum) {
        const float* ap = attnP + ((size_t)(b * 8 + h) << 15);
        const float* kvp = kinv + b * 512 + h * 64;
        #pragma unroll
        for (int i = 0; i < 2; ++i) {
            int e = t + i * 256;           // 512 jobs: d row, 8-c group
            int d = e >> 3, c8 = (e & 7) * 8;
            float s[8] = {};
            #pragma unroll
            for (int ks = 0; ks < NKS; ++ks) {
                const float* pp = &ap[(ks << 12) + d * 64 + c8];
                float4 v0 = *(const float4*)pp;
                float4 v1 = *(const float4*)(pp + 4);
                s[0] += v0.x; s[1] += v0.y; s[2] += v0.z; s[3] += v0.w;
                s[4] += v1.x; s[5] += v1.y; s[6] += v1.z; s[7] += v1.w;
            }
            #pragma unroll
            for (int j = 0; j < 8; ++j)
                sT[c8 + j][d] = (__bf16)(s[j] * kvp[c8 + j]);
        }
    } else {
        const bf16_t* aF = attnF + ((size_t)(b * 8 + h) << 12);
        #pragma unroll
        for (int i = 0; i < 2; ++i) {
            int e = t + i * 256;
            int d = e >> 3, c8 = (e & 7) * 8;
            bf8 v = *(const bf8*)&aF[d * 64 + c8];
            #pragma unroll
            for (int j = 0; j < 8; ++j) sT[c8 + j][d] = v[j];
        }
    }
    __syncthreads();

    const int obase = om * 128 + w * 32;
    f32x4 acc[2][4] = {};
    #pragma unroll
    for (int kk = 0; kk < 2; ++kk) {
        bf8 af[2], bfr[4];
        #pragma unroll
        for (int mi = 0; mi < 2; ++mi)
            af[mi] = *(const bf8*)&Wf[(size_t)(obase + mi * 16 + l16) * NC +
                                      h * 64 + kk * 32 + quad * 8];
        #pragma unroll
        for (int ni = 0; ni < 4; ++ni)
            bfr[ni] = *(const bf8*)&sT[ni * 16 + l16][kk * 32 + quad * 8];
        #pragma unroll
        for (int mi = 0; mi < 2; ++mi)
            #pragma unroll
            for (int ni = 0; ni < 4; ++ni)
                acc[mi][ni] = __builtin_amdgcn_mfma_f32_16x16x32_bf16(
                    af[mi], bfr[ni], acc[mi][ni], 0, 0, 0);
    }
    bf16_t* outp = Wff + ((size_t)b << 18);     // 512*512 per batch
    #pragma unroll
    for (int mi = 0; mi < 2; ++mi)
        #pragma unroll
        for (int ni = 0; ni < 4; ++ni)
            #pragma unroll
            for (int r = 0; r < 4; ++r) {
                int o = obase + mi * 16 + quad * 4 + r;
                int c = ni * 16 + l16;
                outp[(size_t)o * NC + h * 64 + c] = (__bf16)acc[mi][ni][r];
            }
}

// ---------------------------------------------------------------------------
// G: FFN GEMM. grid(32, 4, 8) block 256. A = Wff[b], B = qsm [p][c].
// ybf=1 (full): bf16 y into ws (dead xnT region), ysq from rounded bf16.
// ybf=0 (chunk): fp32 y direct into d_out, ysq from fp32, two-half C-write.
// ---------------------------------------------------------------------------
__global__ __launch_bounds__(256) void
gemm_ffn_kernel(const bf16_t* __restrict__ Wff, const bf16_t* __restrict__ qsm,
                const float* __restrict__ bias, float* __restrict__ outf,
                bf16_t* __restrict__ ybf16, float* __restrict__ ysq, int ybf) {
    const int bn = blockIdx.x, bm = blockIdx.y, b = blockIdx.z;
    const int t = threadIdx.x;
    const int w = t >> 6, ln = t & 63, quad = ln >> 4, l16 = ln & 15;
    const int wm = w >> 1, wn = w & 1;

    __shared__ __align__(16) __bf16 sAB[128 * LDC];
    __bf16* const sA = sAB;
    __bf16* const sB = sAB + 8192;

    f32x4 acc[4][4] = {};
    const bf16_t* Abase = Wff + ((size_t)b << 18) + (size_t)(bm * 128) * NC;
    const bf16_t* Bbase = qsm + (size_t)b * QSTRIDE + (size_t)(bn * 128) * NC;

    const int lrow = ln >> 3;
    const int lkc = ((ln & 7) ^ lrow) * 8;
    const int xr = l16 & 7;

    for (int kt = 0; kt < 8; ++kt) {
        const int k0 = kt * 64;
        #pragma unroll
        for (int i = 0; i < 4; ++i) {
            const int chunk = w * 4 + i;
            const int row = chunk * 8 + lrow;
            gload_lds16(Abase + (size_t)row * NC + k0 + lkc, &sA[chunk * 512]);
            gload_lds16(Bbase + (size_t)row * NC + k0 + lkc, &sB[chunk * 512]);
        }
        __syncthreads();
        #pragma unroll
        for (int ks = 0; ks < 2; ++ks) {
            bf8 af[4], bfr[4];
            const int kx = ((ks * 4 + quad) ^ xr) << 3;
            #pragma unroll
            for (int mi = 0; mi < 4; ++mi)
                af[mi] = *(const bf8*)&sA[(wm * 64 + mi * 16 + l16) * 64 + kx];
            #pragma unroll
            for (int ni = 0; ni < 4; ++ni)
                bfr[ni] = *(const bf8*)&sB[(wn * 64 + ni * 16 + l16) * 64 + kx];
            #pragma unroll
            for (int mi = 0; mi < 4; ++mi)
                #pragma unroll
                for (int ni = 0; ni < 4; ++ni)
                    acc[mi][ni] = __builtin_amdgcn_mfma_f32_16x16x32_bf16(
                        af[mi], bfr[ni], acc[mi][ni], 0, 0, 0);
        }
        __syncthreads();
    }

    float* sq = ysq + (size_t)b * NP;
    const int p0 = bn * 128;
    const int rbase = wm * 64 + quad * 4;

    if (ybf) {
        // bf16 y path (R7-consistent): ysq from rounded bf16, LDS C-tile
        #pragma unroll
        for (int ni = 0; ni < 4; ++ni) {
            const int col = p0 + wn * 64 + ni * 16 + l16;
            float colsq = 0.f;
            #pragma unroll
            for (int mi = 0; mi < 4; ++mi) {
                #pragma unroll
                for (int r = 0; r < 4; ++r) {
                    const int row = bm * 128 + rbase + mi * 16 + r;
                    __bf16 vb = (__bf16)(acc[mi][ni][r] + bias[row]);
                    sAB[(rbase + mi * 16 + r) * LDC + wn * 64 + ni * 16 + l16] = vb;
                    float vf = (float)vb;
                    colsq += vf * vf;
                }
            }
            colsq += __shfl_xor(colsq, 16);
            colsq += __shfl_xor(colsq, 32);
            if (quad == 0) atomicAdd(&sq[col], colsq);
        }
        __syncthreads();
        bf16_t* yb = ybf16 + (size_t)b * QSTRIDE;
        #pragma unroll
        for (int i = 0; i < 8; ++i) {
            int e = t + i * 256;
            int rr = e >> 4, seg = (e & 15) * 8;
            bf8 v = *(const bf8*)&sAB[rr * LDC + seg];
            *(bf8*)&yb[(size_t)(bm * 128 + rr) * NP + p0 + seg] = v;
        }
    } else {
        // fp32 y path (chunk fallback, R9)
        #pragma unroll
        for (int ni = 0; ni < 4; ++ni) {
            const int col = p0 + wn * 64 + ni * 16 + l16;
            float colsq = 0.f;
            #pragma unroll
            for (int mi = 0; mi < 4; ++mi)
                #pragma unroll
                for (int r = 0; r < 4; ++r) {
                    float vf = acc[mi][ni][r] + bias[bm * 128 + rbase + mi * 16 + r];
                    colsq += vf * vf;
                }
            colsq += __shfl_xor(colsq, 16);
            colsq += __shfl_xor(colsq, 32);
            if (quad == 0) atomicAdd(&sq[col], colsq);
        }
        float* sF = (float*)sAB;                    // [64][136] f32 = 34816 B
        float* ob = outf + (size_t)b * QSTRIDE;
        #pragma unroll
        for (int half = 0; half < 2; ++half) {
            __syncthreads();
            if (wm == half) {
                #pragma unroll
                for (int mi = 0; mi < 4; ++mi)
                    #pragma unroll
                    for (int ni = 0; ni < 4; ++ni)
                        #pragma unroll
                        for (int r = 0; r < 4; ++r)
                            sF[(quad * 4 + mi * 16 + r) * 136 + wn * 64 + ni * 16 + l16] =
                                acc[mi][ni][r] +
                                bias[bm * 128 + half * 64 + quad * 4 + mi * 16 + r];
            }
            __syncthreads();
            #pragma unroll
            for (int i = 0; i < 8; ++i) {
                int e = t + i * 256;
                int rr = e >> 5, c4 = (e & 31) * 4;
                float4 v = *(const float4*)&sF[rr * 136 + c4];
                *(float4*)&ob[(size_t)(bm * 128 + half * 64 + rr) * NP + p0 + c4] = v;
            }
        }
    }
}

// ---------------------------------------------------------------------------
// H: final. ybf=1: out = ybf16*inv*g2*sqrtC + x (write-only out).
//          ybf=0: in-place on fp32 out (chunk fallback).
// grid(1024, 8) block 256.
// ---------------------------------------------------------------------------
__global__ __launch_bounds__(256) void
final_kernel(float* __restrict__ out, const bf16_t* __restrict__ ybf16,
             const float* __restrict__ ysq, const float* __restrict__ g2,
             const float* __restrict__ x, int ybf) {
    const int b = blockIdx.y;
    int idx = blockIdx.x * 256 + threadIdx.x;
    int o = idx >> 9;
    int p8 = (idx & 511) * 8;
    float* ob = out + (size_t)b * QSTRIDE;
    const float* xb = x + (size_t)b * QSTRIDE;
    const float* sq = ysq + (size_t)b * NP;

    float gv = g2[o] * SQRTC;
    float4 a = *(const float4*)&xb[(size_t)o * NP + p8];
    float4 b2 = *(const float4*)&xb[(size_t)o * NP + p8 + 4];
    float inb[8];
    #pragma unroll
    for (int j = 0; j < 8; ++j)
        inb[j] = 1.0f / fmaxf(sqrtf(sq[p8 + j]), 1e-12f);

    float y[8];
    if (ybf) {
        const bf16_t* yb = ybf16 + (size_t)b * QSTRIDE;
        bf8 yv = *(const bf8*)&yb[(size_t)o * NP + p8];
        #pragma unroll
        for (int j = 0; j < 8; ++j) y[j] = (float)yv[j];
    } else {
        float4 y0 = *(const float4*)&ob[(size_t)o * NP + p8];
        float4 y1 = *(const float4*)&ob[(size_t)o * NP + p8 + 4];
        y[0] = y0.x; y[1] = y0.y; y[2] = y0.z; y[3] = y0.w;
        y[4] = y1.x; y[5] = y1.y; y[6] = y1.z; y[7] = y1.w;
    }

    float4 r0, r1;
    r0.x = y[0] * inb[0] * gv + a.x;
    r0.y = y[1] * inb[1] * gv + a.y;
    r0.z = y[2] * inb[2] * gv + a.z;
    r0.w = y[3] * inb[3] * gv + a.w;
    r1.x = y[4] * inb[4] * gv + b2.x;
    r1.y = y[5] * inb[5] * gv + b2.y;
    r1.z = y[6] * inb[6] * gv + b2.z;
    r1.w = y[7] * inb[7] * gv + b2.w;
    *(float4*)&ob[(size_t)o * NP + p8] = r0;
    *(float4*)&ob[(size_t)o * NP + p8 + 4] = r1;
}

// ---------------------------------------------------------------------------
extern "C" void kernel_launch(void* const* d_in, const int* in_sizes, int n_in,
                              void* d_out, int out_size, void* d_ws, size_t ws_size,
                              hipStream_t stream) {
    const float* x     = (const float*)d_in[0];
    const float* g     = (const float*)d_in[1];
    const float* qkv_w = (const float*)d_in[2];
    const float* ffn_w = (const float*)d_in[3];
    const float* ffn_b = (const float*)d_in[4];
    const float* ffn_g = (const float*)d_in[5];
    float* out = (float*)d_out;
    bf16_t* kv = (bf16_t*)d_out;     // K,V bf16; later Wff (full) / fp32 y

    const size_t FULL_BYTES =
        (8 * QSTRIDE + 8 * QSTRIDE + 786432 + 262144) * sizeof(bf16_t) +
        (8 * 512 + 8 * 512 + 8 * (size_t)NP) * sizeof(float);
    const bool full = ws_size >= FULL_BYTES;

    bf16_t* q    = (bf16_t*)d_ws;                    // qsm, [p][c] per batch
    bf16_t* xnT  = q + 8 * QSTRIDE;                  // 8 or 2 batches
    bf16_t* Wg   = xnT + (full ? 8 : 2) * QSTRIDE;   // 786432 bf16
    float*  attnP = (float*)xnT;                     // 8.39 MB (xnT dead)
    bf16_t* y16  = xnT;                              // full: bf16 y (attnP dead)
    bf16_t* attnF = Wg;                              // chunk only (Wg dead)
    bf16_t* WffC = xnT;                              // chunk: Wff (attnP dead)
    bf16_t* WffF = kv;                               // full: Wff in d_out (K dead)
    bf16_t* Wf   = Wg + 786432;                      // 262144 bf16
    float*  kmax = (float*)(Wf + 262144);            // 8*512 f32
    float*  kinv = kmax + 8 * 512;                   // 8*512 f32
    float*  ysq  = kinv + 8 * 512;                   // 8*4096 f32

    if (full) {
        norm_transpose_kernel<<<dim3(128, 8), 512, 0, stream>>>(
            x, xnT, qkv_w, g, ffn_w, Wg, Wf, 1);
        gemm_qkv_kernel<<<dim3(32, 12, 8), 256, 0, stream>>>(Wg, xnT, q, kv);
        kstats_kernel<<<dim3(512, 8), 256, 0, stream>>>(kv, kmax, kinv);
        attn_kernel<<<dim3(8, NKS, 8), 256, 0, stream>>>(kv, kmax, attnP, ysq);
        wmix_kernel<<<dim3(4, 8, 8), 256, 0, stream>>>(
            Wf, attnP, kinv, nullptr, WffF, 1);
        gemm_ffn_kernel<<<dim3(32, 4, 8), 256, 0, stream>>>(
            WffF, q, ffn_b, nullptr, y16, ysq, 1);
        final_kernel<<<dim3(1024, 8), 256, 0, stream>>>(
            out, y16, ysq, ffn_g, x, 1);
    } else {
        wconv_kernel<<<dim3(1024), 256, 0, stream>>>(qkv_w, g, ffn_w, Wg, Wf);
        for (int c = 0; c < 4; ++c) {
            norm_transpose_kernel<<<dim3(128, 2), 512, 0, stream>>>(
                x + (size_t)(2 * c) * QSTRIDE, xnT,
                qkv_w, g, ffn_w, Wg, Wf, 0);
            gemm_qkv_kernel<<<dim3(32, 12, 2), 256, 0, stream>>>(
                Wg, xnT, q + (size_t)(2 * c) * QSTRIDE,
                kv + (size_t)(2 * c) * KVSTRIDE);
        }
        kstats_kernel<<<dim3(512, 8), 256, 0, stream>>>(kv, kmax, kinv);
        attn_kernel<<<dim3(8, NKS, 8), 256, 0, stream>>>(kv, kmax, attnP, ysq);
        attnsum_kernel<<<dim3(64, 4), 256, 0, stream>>>(attnP, kinv, attnF, ysq);
        wmix_kernel<<<dim3(4, 8, 8), 256, 0, stream>>>(
            Wf, attnP, kinv, attnF, WffC, 0);
        gemm_ffn_kernel<<<dim3(32, 4, 8), 256, 0, stream>>>(
            WffC, q, ffn_b, out, nullptr, ysq, 0);
        final_kernel<<<dim3(1024, 8), 256, 0, stream>>>(
            out, nullptr, ysq, ffn_g, x, 0);
    }
}